// Round 10
// baseline (5045.956 us; speedup 1.0000x reference)
//
#include <hip/hip_runtime.h>
#include <hip/hip_bf16.h>

// Problem dims
#define BB   256
#define TIN  336
#define TOUT 96
#define FF   32
#define HH   256

#define NGS 16   // gate-column slices (gi)
#define NBG 16   // batch groups (gb)
#define RPG 16   // batch rows per group
#define TPB 256  // 4 waves; wave nt owns 16 cols (4 hh x 4 gates), full K

#define KB0 9        // enc L0: K=288 = [x(32) | h0(256)]
#define KB1 16       // K=512 phases
#define ASTRIDE 520  // A-tile row stride (bf16)
#define XSTRIDE 40   // X-tile row stride (bf16)

// ws layout in ushort units. Weight regions: [gi][nt][kb][lane][8], col cl=(hh_l<<2)|gate
#define N_E0   294912                 // 16*4*9*64*8
#define N_K512 524288                 // 16*4*16*64*8
#define N_DX   32768                  // 16*4*1*64*8
#define U_E0   0
#define U_E1   (U_E0 + N_E0)          // 294912  enc L1
#define U_D0   (U_E1 + N_K512)        // 819200  dec L0' = [Whh0 | W_eff]
#define U_D1   (U_D0 + N_K512)        // 1343488 dec L1
#define U_DX   (U_D1 + N_K512)        // 1867776 dec Wih0 (K=32)
#define U_END  (U_DX + N_DX)          // 1900544
#define HPAR   65536                  // one parity buffer: 256x256 bf16
#define U_H0   U_END                  // h0 parity x2
#define U_H1   (U_H0 + 2*HPAR)       // h1 parity x2 (encoder)
#define U_HD   (U_H1 + 2*HPAR)       // decoder h1 per-step x96
#define U_CTR  (U_HD + 96*HPAR)      // flags: [gb][64 dwords]
#define U_ZEND (U_CTR + 4096)

typedef __bf16 bf16x8 __attribute__((ext_vector_type(8)));
typedef float  f32x4  __attribute__((ext_vector_type(4)));

__device__ __forceinline__ float sigf(float x) { return 1.f / (1.f + __expf(-x)); }
__device__ __forceinline__ float tanhfast(float x) { return 1.f - 2.f / (__expf(2.f * x) + 1.f); }
__device__ __forceinline__ unsigned short f2bf(float f) {   // RNE bf16
    union { float f; unsigned u; } v; v.f = f;
    unsigned r = v.u + 0x7FFF + ((v.u >> 16) & 1);
    return (unsigned short)(r >> 16);
}
__device__ __forceinline__ float sel4(f32x4 a, int i) {
    return i == 0 ? a[0] : (i == 1 ? a[1] : (i == 2 ? a[2] : a[3]));
}
__device__ __forceinline__ float pick4(float a0, float a1, float a2, float a3, int i) {
    return i == 0 ? a0 : (i == 1 ? a1 : (i == 2 ? a2 : a3));
}
// coherence-point loads (bypass L1/L2); pair with write-through producer stores
__device__ __forceinline__ void ldg_sc2(const void* p0, const void* p1, uint4& a, uint4& b) {
    asm volatile("global_load_dwordx4 %0, %2, off sc0 sc1\n\t"
                 "global_load_dwordx4 %1, %3, off sc0 sc1\n\t"
                 "s_waitcnt vmcnt(0)"
                 : "=v"(a), "=v"(b) : "v"(p0), "v"(p1) : "memory");
}
__device__ __forceinline__ void ldg_sc4(const void* p0, const void* p1,
                                        const void* p2, const void* p3,
                                        uint4& a, uint4& b, uint4& c, uint4& d) {
    asm volatile("global_load_dwordx4 %0, %4, off sc0 sc1\n\t"
                 "global_load_dwordx4 %1, %5, off sc0 sc1\n\t"
                 "global_load_dwordx4 %2, %6, off sc0 sc1\n\t"
                 "global_load_dwordx4 %3, %7, off sc0 sc1\n\t"
                 "s_waitcnt vmcnt(0)"
                 : "=v"(a), "=v"(b), "=v"(c), "=v"(d)
                 : "v"(p0), "v"(p1), "v"(p2), "v"(p3) : "memory");
}

// ---- prep: bf16 MFMA-fragment weights, col map cl=(hh_l<<2)|gate; zero h/flags ----
__global__ void prep_kernel(const float* __restrict__ eWih0, const float* __restrict__ eWhh0,
                            const float* __restrict__ eWih1, const float* __restrict__ eWhh1,
                            const float* __restrict__ dWih0, const float* __restrict__ dWhh0,
                            const float* __restrict__ dWih1, const float* __restrict__ dWhh1,
                            const float* __restrict__ Wout,  float* __restrict__ wsf)
{
    unsigned short* wsu = (unsigned short*)wsf;
    for (long u = (long)blockIdx.x * blockDim.x + threadIdx.x; u < (long)U_END;
         u += (long)gridDim.x * blockDim.x) {
        int region; long l;
        if (u < U_E1)      { region = 0; l = u - U_E0; }
        else if (u < U_D0) { region = 1; l = u - U_E1; }
        else if (u < U_D1) { region = 2; l = u - U_D0; }
        else if (u < U_DX) { region = 3; l = u - U_D1; }
        else               { region = 4; l = u - U_DX; }
        const int KB = (region == 0) ? KB0 : (region == 4 ? 1 : KB1);
        int j = (int)(l & 7), lane = (int)((l >> 3) & 63);
        long rem = l >> 9;
        int kb = (int)(rem % KB), q = (int)(rem / KB);
        int nt = q & 3, gi = q >> 2;
        int k  = kb * 32 + ((lane >> 4) << 3) + j;
        int cl = lane & 15;
        int gate = cl & 3, hh = nt * 4 + (cl >> 2);
        int gj = gate * 256 + gi * 16 + hh;
        float v;
        if (region == 0)      v = (k < 32)  ? eWih0[gj * 32 + k]  : eWhh0[gj * 256 + (k - 32)];
        else if (region == 1) v = (k < 256) ? eWih1[gj * 256 + k] : eWhh1[gj * 256 + (k - 256)];
        else if (region == 2) {
            if (k < 256) v = dWhh0[gj * 256 + k];
            else {                               // W_eff = dWih0 . Wout
                float acc = 0.f; int kk = k - 256;
                #pragma unroll 8
                for (int f = 0; f < 32; ++f) acc += dWih0[gj * 32 + f] * Wout[f * 256 + kk];
                v = acc;
            }
        }
        else if (region == 3) v = (k < 256) ? dWih1[gj * 256 + k] : dWhh1[gj * 256 + (k - 256)];
        else                  v = dWih0[gj * 32 + k];      // K=32
        wsu[u] = f2bf(v);
    }
    for (long z = (long)blockIdx.x * blockDim.x + threadIdx.x; z < (long)(4 * HPAR);
         z += (long)gridDim.x * blockDim.x)
        wsu[U_H0 + z] = 0;
    for (long z = (long)blockIdx.x * blockDim.x + threadIdx.x; z < 4096;
         z += (long)gridDim.x * blockDim.x)
        wsu[U_CTR + z] = 0;
}

// ---- persistent seq2seq: 256 wgs x 4 waves; in-wave cell update; barrier-free gsync ----
__global__ __launch_bounds__(TPB, 1) void lstm_main(
    const float* __restrict__ x,
    const float* __restrict__ eb0, const float* __restrict__ eb1,
    const float* __restrict__ db0, const float* __restrict__ db1,
    const float* __restrict__ Wout, const float* __restrict__ bout,
    const float* __restrict__ dWih0,
    float* __restrict__ ws, float* __restrict__ out)
{
    const int gi = blockIdx.x >> 4;
    const int gb = blockIdx.x & 15;   // stride-16 blocks -> same XCD per group

    unsigned short* wsu = (unsigned short*)ws;
    const unsigned short* h0u = wsu + U_H0;
    const unsigned short* h1u = wsu + U_H1;
    const unsigned short* hdu = wsu + U_HD;
    unsigned* flagbase = (unsigned*)(wsu + U_CTR) + gb * 64;

    const int t  = threadIdx.x;
    const int wv = t >> 6;            // wave = N-tile nt
    const int ln = t & 63;
    const int nt = wv;
    const int arow = ln & 15, ak = (ln >> 4) << 3;
    const int g = ln & 3;             // gate role
    const int hh = nt * 4 + ((ln >> 2) & 3);
    const int myrow = gb * 16 + (ln >> 4) * 4 + g;     // row this lane updates
    const int mycol = gi * 16 + hh;

    __shared__ __align__(16) unsigned short Atile[16 * ASTRIDE];   // 16.25 KB
    __shared__ __align__(16) unsigned short Xtile[16 * XSTRIDE];   // 1.25 KB

    // per-lane biases (gates 0..3 at (gi,hh))
    float bE0[4], bE1[4], bD0p[4], bDe[4], bD1[4];
    #pragma unroll
    for (int gg = 0; gg < 4; ++gg) {
        const int gj = gg * 256 + gi * 16 + hh;
        bE0[gg] = eb0[gj]; bE1[gg] = eb1[gj]; bD0p[gg] = db0[gj]; bD1[gg] = db1[gj];
        float be = db0[gj];
        #pragma unroll 8
        for (int f = 0; f < 32; ++f) be += dWih0[gj * 32 + f] * bout[f];
        bDe[gg] = be;
    }
    float creg[2] = {0.f, 0.f};       // register cell state (this lane's row,hh)

    bf16x8 Brg0[16], Brg1[16], Bx0;
    auto loadB = [&](long ubase, int KB, bf16x8* B) {
        for (int i = 0; i < KB; ++i)
            B[i] = *(const bf16x8*)(wsu + ubase + ((long)(nt * KB + i) * 64 + ln) * 8);
    };

    int posts = 0;
    auto gsync = [&]() {              // barrier-free: per-wave flags, all-wave poll
        ++posts;
        asm volatile("s_waitcnt vmcnt(0)" ::: "memory");   // own h-stores at IC
        if (ln == 0)
            __hip_atomic_store(flagbase + (gi * 4 + wv), (unsigned)posts,
                               __ATOMIC_RELAXED, __HIP_MEMORY_SCOPE_AGENT);
        for (;;) {
            unsigned v = __hip_atomic_load(flagbase + ln, __ATOMIC_RELAXED,
                                           __HIP_MEMORY_SCOPE_AGENT);
            if (__all((int)(v >= (unsigned)posts))) break;
            __builtin_amdgcn_s_sleep(1);
        }
    };

    // stage helpers: 256 threads, r = t>>4, c16 = t&15 (32B chunk per row)
    const int sr = t >> 4, sc16 = t & 15;
    auto stageEnc = [&](const unsigned short* h0src, const unsigned short* h1src, int xs) {
        const unsigned short* p0 = h0src + (long)(gb * 16 + sr) * 256 + sc16 * 16;
        const unsigned short* p1 = h1src + (long)(gb * 16 + sr) * 256 + sc16 * 16;
        uint4 a, b, c, d;
        ldg_sc4(p0, p0 + 8, p1, p1 + 8, a, b, c, d);
        float2 xv = {0.f, 0.f};
        if (xs >= 0) xv = *(const float2*)(x + ((long)(gb * 16 + sr) * TIN + xs) * FF + sc16 * 2);
        *(uint4*)(Atile + sr * ASTRIDE + sc16 * 16) = a;
        *(uint4*)(Atile + sr * ASTRIDE + sc16 * 16 + 8) = b;
        *(uint4*)(Atile + sr * ASTRIDE + 256 + sc16 * 16) = c;
        *(uint4*)(Atile + sr * ASTRIDE + 256 + sc16 * 16 + 8) = d;
        if (xs >= 0) {
            unsigned pv = (unsigned)f2bf(xv.x) | ((unsigned)f2bf(xv.y) << 16);
            *(unsigned*)(Xtile + sr * XSTRIDE + sc16 * 2) = pv;
        }
    };
    auto stageOne = [&](const unsigned short* src, int colbase) {
        const unsigned short* p = src + (long)(gb * 16 + sr) * 256 + sc16 * 16;
        uint4 a, b;
        ldg_sc2(p, p + 8, a, b);
        *(uint4*)(Atile + sr * ASTRIDE + colbase + sc16 * 16) = a;
        *(uint4*)(Atile + sr * ASTRIDE + colbase + sc16 * 16 + 8) = b;
    };
    auto stageTwo = [&](const unsigned short* s0, int cb0, const unsigned short* s1, int cb1) {
        const unsigned short* p0 = s0 + (long)(gb * 16 + sr) * 256 + sc16 * 16;
        const unsigned short* p1 = s1 + (long)(gb * 16 + sr) * 256 + sc16 * 16;
        uint4 a, b, c, d;
        ldg_sc4(p0, p0 + 8, p1, p1 + 8, a, b, c, d);
        *(uint4*)(Atile + sr * ASTRIDE + cb0 + sc16 * 16) = a;
        *(uint4*)(Atile + sr * ASTRIDE + cb0 + sc16 * 16 + 8) = b;
        *(uint4*)(Atile + sr * ASTRIDE + cb1 + sc16 * 16) = c;
        *(uint4*)(Atile + sr * ASTRIDE + cb1 + sc16 * 16 + 8) = d;
    };
    auto stageZero = [&](int colbase) {
        uint4 z = {0u, 0u, 0u, 0u};
        *(uint4*)(Atile + sr * ASTRIDE + colbase + sc16 * 16) = z;
        *(uint4*)(Atile + sr * ASTRIDE + colbase + sc16 * 16 + 8) = z;
    };
    auto stageX = [&](int xs) {
        float2 xv = *(const float2*)(x + ((long)(gb * 16 + sr) * TIN + xs) * FF + sc16 * 2);
        unsigned pv = (unsigned)f2bf(xv.x) | ((unsigned)f2bf(xv.y) << 16);
        *(unsigned*)(Xtile + sr * XSTRIDE + sc16 * 2) = pv;
    };

    // MFMA phase, full K per wave; in-wave gate exchange; register cell; 1 ushort store
    auto phase = [&](const bf16x8* B, int KB, bool withX, const float* bias, int layer,
                     unsigned short* hdst, bool addY0) {
        f32x4 acc = {0.f, 0.f, 0.f, 0.f};
        #pragma unroll
        for (int kb = 0; kb < 16; ++kb) {
            if (kb < KB) {
                bf16x8 a;
                if (withX && kb == 0) a = *(const bf16x8*)(Xtile + arow * XSTRIDE + ak);
                else {
                    const int koff = (withX ? (kb - 1) : kb) * 32;
                    a = *(const bf16x8*)(Atile + arow * ASTRIDE + koff + ak);
                }
                acc = __builtin_amdgcn_mfma_f32_16x16x32_bf16(a, B[kb], acc, 0, 0, 0);
            }
        }
        if (addY0) {
            bf16x8 a = *(const bf16x8*)(Xtile + arow * XSTRIDE + ak);
            acc = __builtin_amdgcn_mfma_f32_16x16x32_bf16(a, Bx0, acc, 0, 0, 0);
        }
        // gate exchange: lane handles row offset g; partner role g^d sends acc[(g^d)^d]=acc[g]
        float own = sel4(acc, g);
        float t1 = __shfl_xor(sel4(acc, g ^ 1), 1);
        float t2 = __shfl_xor(sel4(acc, g ^ 2), 2);
        float t3 = __shfl_xor(sel4(acc, g ^ 3), 3);
        float xi = pick4(own, t1, t2, t3, g)     + bias[0];
        float xf = pick4(own, t1, t2, t3, g ^ 1) + bias[1];
        float xg = pick4(own, t1, t2, t3, g ^ 2) + bias[2];
        float xo = pick4(own, t1, t2, t3, g ^ 3) + bias[3];
        float c  = creg[layer];
        float cn = sigf(xf) * c + sigf(xi) * tanhfast(xg);
        creg[layer] = cn;
        float hv = sigf(xo) * tanhfast(cn);
        __hip_atomic_store(hdst + (long)myrow * 256 + mycol, f2bf(hv),
                           __ATOMIC_RELAXED, __HIP_MEMORY_SCOPE_AGENT);
    };

    // ---- init: enc B-frags; h0(-1)=0 in Atile; Xtile = x(0) ----
    loadB(U_E0 + (long)gi * 18432, KB0, Brg0);
    loadB(U_E1 + (long)gi * 32768, KB1, Brg1);
    stageZero(0);
    stageX(0);
    __syncthreads();

    // ---- encoder: 1 gsync/step ----
    for (int s = 0; s < TIN; ++s) {
        const int rp = s & 1, wp = rp ^ 1;
        phase(Brg0, KB0, true, bE0, 0, wsu + U_H0 + (long)wp * HPAR, false);
        gsync();                                   // publishes h0(s) (+ h1(s-1) earlier)
        stageEnc(h0u + (long)wp * HPAR, h1u + (long)rp * HPAR, (s + 1 < TIN) ? s + 1 : -1);
        __syncthreads();
        phase(Brg1, KB1, false, bE1, 1, wsu + U_H1 + (long)wp * HPAR, false);
    }

    // ---- pre-decoder: dec B-frags, Bx0, y0 -> Xtile ----
    loadB(U_D0 + (long)gi * 32768, KB1, Brg0);
    loadB(U_D1 + (long)gi * 32768, KB1, Brg1);
    Bx0 = *(const bf16x8*)(wsu + U_DX + (long)gi * 2048 + ((long)nt * 64 + ln) * 8);
    stageX(TIN - 1);                               // y0 = x[:, -1, :]

    // ---- decoder: 2 gsyncs/step; h0(s-1) persists in Atile cols 0..255 ----
    for (int s = TIN; s < TIN + TOUT; ++s) {
        const int wp = (s & 1) ^ 1, td = s - TIN;
        gsync();                                   // publishes h1(s-1)
        if (td == 0) stageZero(256);               // W_eff·0; y0 via addY0
        else stageOne(hdu + (long)(td - 1) * HPAR, 256);
        __syncthreads();
        phase(Brg0, KB1, false, (td == 0) ? bD0p : bDe, 0,
              wsu + U_H0 + (long)wp * HPAR, td == 0);
        gsync();                                   // publishes h0(s)
        if (td == 0) stageTwo(h0u + (long)wp * HPAR, 0, h1u + 0 * HPAR, 256);
        else stageOne(h0u + (long)wp * HPAR, 0);
        __syncthreads();
        phase(Brg1, KB1, false, bD1, 1, wsu + U_HD + (long)td * HPAR, false);
    }

    // ---- final sync: all h1dec published ----
    gsync();

    // ---- deferred y pass: f = {2gi, 2gi+1}, rows of gb; shuffle-reduce K over 16 lanes ----
    {
        const int r = t >> 4, kc = t & 15;
        const int f0 = gi * 2, f1 = f0 + 1;
        float w0[16], w1[16];
        #pragma unroll
        for (int i = 0; i < 16; ++i) {
            w0[i] = Wout[(long)f0 * 256 + kc * 16 + i];
            w1[i] = Wout[(long)f1 * 256 + kc * 16 + i];
        }
        const float bo0 = bout[f0], bo1 = bout[f1];
        for (int td = 0; td < TOUT; ++td) {
            const unsigned short* hp = hdu + (long)td * HPAR + (long)(gb * 16 + r) * 256 + kc * 16;
            uint4 ua = *(const uint4*)hp;
            uint4 ub = *(const uint4*)(hp + 8);
            unsigned wds[8] = {ua.x, ua.y, ua.z, ua.w, ub.x, ub.y, ub.z, ub.w};
            float a0 = 0.f, a1 = 0.f;
            #pragma unroll
            for (int j = 0; j < 8; ++j) {
                float lo = __uint_as_float(wds[j] << 16);
                float hi = __uint_as_float(wds[j] & 0xffff0000u);
                a0 = fmaf(lo, w0[2 * j], a0); a0 = fmaf(hi, w0[2 * j + 1], a0);
                a1 = fmaf(lo, w1[2 * j], a1); a1 = fmaf(hi, w1[2 * j + 1], a1);
            }
            #pragma unroll
            for (int off = 1; off < 16; off <<= 1) {
                a0 += __shfl_xor(a0, off);
                a1 += __shfl_xor(a1, off);
            }
            if (kc == 0) {
                float2 yv = {a0 + bo0, a1 + bo1};
                *(float2*)(out + ((long)(gb * 16 + r) * TOUT + td) * FF + f0) = yv;
            }
        }
    }
}

extern "C" void kernel_launch(void* const* d_in, const int* in_sizes, int n_in,
                              void* d_out, int out_size, void* d_ws, size_t ws_size,
                              hipStream_t stream) {
    const float* x     = (const float*)d_in[0];
    const float* eWih0 = (const float*)d_in[1];
    const float* eWhh0 = (const float*)d_in[2];
    const float* eb0   = (const float*)d_in[3];
    const float* eWih1 = (const float*)d_in[4];
    const float* eWhh1 = (const float*)d_in[5];
    const float* eb1   = (const float*)d_in[6];
    const float* dWih0 = (const float*)d_in[7];
    const float* dWhh0 = (const float*)d_in[8];
    const float* db0   = (const float*)d_in[9];
    const float* dWih1 = (const float*)d_in[10];
    const float* dWhh1 = (const float*)d_in[11];
    const float* db1   = (const float*)d_in[12];
    const float* dWout = (const float*)d_in[13];
    const float* dbout = (const float*)d_in[14];
    float* ws = (float*)d_ws;
    float* out = (float*)d_out;

    prep_kernel<<<1024, 256, 0, stream>>>(eWih0, eWhh0, eWih1, eWhh1,
                                          dWih0, dWhh0, dWih1, dWhh1, dWout, ws);
    lstm_main<<<NGS * NBG, TPB, 0, stream>>>(x, eb0, eb1, db0, db1,
                                             dWout, dbout, dWih0, ws, out);
}

// Round 11
// 4868.503 us; speedup vs baseline: 1.0364x; 1.0364x over previous
//
#include <hip/hip_runtime.h>
#include <hip/hip_bf16.h>

// Problem dims
#define BB   256
#define TIN  336
#define TOUT 96
#define FF   32
#define HH   256

#define NGS 16   // gate-column slices (gi)
#define NBG 16   // batch groups (gb)
#define RPG 16   // batch rows per group
#define TPB 256  // 4 waves; wave nt owns 16 cols (4 hh x 4 gates), full K

#define KB0 9        // enc L0: K=288 = [x(32) | h0(256)]
#define KB1 16       // K=512 phases
#define ASTRIDE 520  // A-tile row stride (bf16)
#define XSTRIDE 40   // X-tile row stride (bf16)

// ws layout in ushort units. Weight regions: [gi][nt][kb][lane][8], col cl=(hh_l<<2)|gate
#define N_E0   294912                 // 16*4*9*64*8
#define N_K512 524288                 // 16*4*16*64*8
#define N_DX   32768                  // 16*4*1*64*8
#define U_E0   0
#define U_E1   (U_E0 + N_E0)          // 294912  enc L1
#define U_D0   (U_E1 + N_K512)        // 819200  dec L0' = [Whh0 | W_eff]
#define U_D1   (U_D0 + N_K512)        // 1343488 dec L1
#define U_DX   (U_D1 + N_K512)        // 1867776 dec Wih0 (K=32)
#define U_END  (U_DX + N_DX)          // 1900544
#define HPAR   65536                  // one parity buffer: 256x256 bf16
#define U_H0   U_END                  // h0 parity x2
#define U_H1   (U_H0 + 2*HPAR)       // h1 parity x2 (encoder)
#define U_HD   (U_H1 + 2*HPAR)       // decoder h1 per-step x96
#define U_CTR  (U_HD + 96*HPAR)      // flags: [gb][64 dwords]
#define U_ZEND (U_CTR + 4096)

typedef __bf16 bf16x8 __attribute__((ext_vector_type(8)));
typedef float  f32x4  __attribute__((ext_vector_type(4)));

__device__ __forceinline__ float sigf(float x) { return 1.f / (1.f + __expf(-x)); }
__device__ __forceinline__ float tanhfast(float x) { return 1.f - 2.f / (__expf(2.f * x) + 1.f); }
__device__ __forceinline__ unsigned short f2bf(float f) {   // RNE bf16
    union { float f; unsigned u; } v; v.f = f;
    unsigned r = v.u + 0x7FFF + ((v.u >> 16) & 1);
    return (unsigned short)(r >> 16);
}
__device__ __forceinline__ float sel4(f32x4 a, int i) {
    return i == 0 ? a[0] : (i == 1 ? a[1] : (i == 2 ? a[2] : a[3]));
}
__device__ __forceinline__ float pick4(float a0, float a1, float a2, float a3, int i) {
    return i == 0 ? a0 : (i == 1 ? a1 : (i == 2 ? a2 : a3));
}
// coherence-point loads (bypass L1/L2); pair with write-through producer stores
__device__ __forceinline__ void ldg_sc2(const void* p0, const void* p1, uint4& a, uint4& b) {
    asm volatile("global_load_dwordx4 %0, %2, off sc0 sc1\n\t"
                 "global_load_dwordx4 %1, %3, off sc0 sc1\n\t"
                 "s_waitcnt vmcnt(0)"
                 : "=v"(a), "=v"(b) : "v"(p0), "v"(p1) : "memory");
}
__device__ __forceinline__ void ldg_sc4(const void* p0, const void* p1,
                                        const void* p2, const void* p3,
                                        uint4& a, uint4& b, uint4& c, uint4& d) {
    asm volatile("global_load_dwordx4 %0, %4, off sc0 sc1\n\t"
                 "global_load_dwordx4 %1, %5, off sc0 sc1\n\t"
                 "global_load_dwordx4 %2, %6, off sc0 sc1\n\t"
                 "global_load_dwordx4 %3, %7, off sc0 sc1\n\t"
                 "s_waitcnt vmcnt(0)"
                 : "=v"(a), "=v"(b), "=v"(c), "=v"(d)
                 : "v"(p0), "v"(p1), "v"(p2), "v"(p3) : "memory");
}

// ---- prep: bf16 MFMA-fragment weights, col map cl=(hh_l<<2)|gate; zero h/flags ----
__global__ void prep_kernel(const float* __restrict__ eWih0, const float* __restrict__ eWhh0,
                            const float* __restrict__ eWih1, const float* __restrict__ eWhh1,
                            const float* __restrict__ dWih0, const float* __restrict__ dWhh0,
                            const float* __restrict__ dWih1, const float* __restrict__ dWhh1,
                            const float* __restrict__ Wout,  float* __restrict__ wsf)
{
    unsigned short* wsu = (unsigned short*)wsf;
    for (long u = (long)blockIdx.x * blockDim.x + threadIdx.x; u < (long)U_END;
         u += (long)gridDim.x * blockDim.x) {
        int region; long l;
        if (u < U_E1)      { region = 0; l = u - U_E0; }
        else if (u < U_D0) { region = 1; l = u - U_E1; }
        else if (u < U_D1) { region = 2; l = u - U_D0; }
        else if (u < U_DX) { region = 3; l = u - U_D1; }
        else               { region = 4; l = u - U_DX; }
        const int KB = (region == 0) ? KB0 : (region == 4 ? 1 : KB1);
        int j = (int)(l & 7), lane = (int)((l >> 3) & 63);
        long rem = l >> 9;
        int kb = (int)(rem % KB), q = (int)(rem / KB);
        int nt = q & 3, gi = q >> 2;
        int k  = kb * 32 + ((lane >> 4) << 3) + j;
        int cl = lane & 15;
        int gate = cl & 3, hh = nt * 4 + (cl >> 2);
        int gj = gate * 256 + gi * 16 + hh;
        float v;
        if (region == 0)      v = (k < 32)  ? eWih0[gj * 32 + k]  : eWhh0[gj * 256 + (k - 32)];
        else if (region == 1) v = (k < 256) ? eWih1[gj * 256 + k] : eWhh1[gj * 256 + (k - 256)];
        else if (region == 2) {
            if (k < 256) v = dWhh0[gj * 256 + k];
            else {                               // W_eff = dWih0 . Wout
                float acc = 0.f; int kk = k - 256;
                #pragma unroll 8
                for (int f = 0; f < 32; ++f) acc += dWih0[gj * 32 + f] * Wout[f * 256 + kk];
                v = acc;
            }
        }
        else if (region == 3) v = (k < 256) ? dWih1[gj * 256 + k] : dWhh1[gj * 256 + (k - 256)];
        else                  v = dWih0[gj * 32 + k];      // K=32
        wsu[u] = f2bf(v);
    }
    for (long z = (long)blockIdx.x * blockDim.x + threadIdx.x; z < (long)(4 * HPAR);
         z += (long)gridDim.x * blockDim.x)
        wsu[U_H0 + z] = 0;
    for (long z = (long)blockIdx.x * blockDim.x + threadIdx.x; z < 4096;
         z += (long)gridDim.x * blockDim.x)
        wsu[U_CTR + z] = 0;
}

// ---- persistent seq2seq: 256 wgs x 4 waves; in-wave cell update; barrier-free gsync ----
__global__ __launch_bounds__(TPB, 1) void lstm_main(
    const float* __restrict__ x,
    const float* __restrict__ eb0, const float* __restrict__ eb1,
    const float* __restrict__ db0, const float* __restrict__ db1,
    const float* __restrict__ Wout, const float* __restrict__ bout,
    const float* __restrict__ dWih0,
    float* __restrict__ ws, float* __restrict__ out)
{
    const int gi = blockIdx.x >> 4;
    const int gb = blockIdx.x & 15;   // stride-16 blocks -> same XCD per group

    unsigned short* wsu = (unsigned short*)ws;
    const unsigned short* h0u = wsu + U_H0;
    const unsigned short* h1u = wsu + U_H1;
    const unsigned short* hdu = wsu + U_HD;
    unsigned* flagbase = (unsigned*)(wsu + U_CTR) + gb * 64;

    const int t  = threadIdx.x;
    const int wv = t >> 6;            // wave = N-tile nt
    const int ln = t & 63;
    const int nt = wv;
    const int arow = ln & 15, ak = (ln >> 4) << 3;
    const int g = ln & 3;             // gate role
    const int hh = nt * 4 + ((ln >> 2) & 3);
    const int myrow = gb * 16 + (ln >> 4) * 4 + g;     // row this lane updates
    const int mycol = gi * 16 + hh;
    (void)mycol;

    __shared__ __align__(16) unsigned short Atile[16 * ASTRIDE];   // 16.25 KB
    __shared__ __align__(16) unsigned short Xtile[16 * XSTRIDE];   // 1.25 KB

    // per-lane biases (gates 0..3 at (gi,hh))
    float bE0[4], bE1[4], bD0p[4], bDe[4], bD1[4];
    #pragma unroll
    for (int gg = 0; gg < 4; ++gg) {
        const int gj = gg * 256 + gi * 16 + hh;
        bE0[gg] = eb0[gj]; bE1[gg] = eb1[gj]; bD0p[gg] = db0[gj]; bD1[gg] = db1[gj];
        float be = db0[gj];
        #pragma unroll 8
        for (int f = 0; f < 32; ++f) be += dWih0[gj * 32 + f] * bout[f];
        bDe[gg] = be;
    }
    float creg[2] = {0.f, 0.f};       // register cell state (this lane's row,hh)

    bf16x8 Brg0[16], Brg1[16], Bx0;
    auto loadB = [&](long ubase, int KB, bf16x8* B) {
        for (int i = 0; i < KB; ++i)
            B[i] = *(const bf16x8*)(wsu + ubase + ((long)(nt * KB + i) * 64 + ln) * 8);
    };

    int posts = 0;
    auto gsync = [&]() {              // barrier-free: per-wave flags, all-wave poll
        ++posts;
        asm volatile("s_waitcnt vmcnt(0)" ::: "memory");   // own h-stores at IC
        if (ln == 0)
            __hip_atomic_store(flagbase + (gi * 4 + wv), (unsigned)posts,
                               __ATOMIC_RELAXED, __HIP_MEMORY_SCOPE_AGENT);
        for (;;) {
            unsigned v = __hip_atomic_load(flagbase + ln, __ATOMIC_RELAXED,
                                           __HIP_MEMORY_SCOPE_AGENT);
            if (__all((int)(v >= (unsigned)posts))) break;
            __builtin_amdgcn_s_sleep(1);
        }
    };

    // stage helpers: 256 threads, r = t>>4, c16 = t&15 (32B chunk per row)
    const int sr = t >> 4, sc16 = t & 15;
    auto stageEnc = [&](const unsigned short* h0src, const unsigned short* h1src, int xs) {
        const unsigned short* p0 = h0src + (long)(gb * 16 + sr) * 256 + sc16 * 16;
        const unsigned short* p1 = h1src + (long)(gb * 16 + sr) * 256 + sc16 * 16;
        uint4 a, b, c, d;
        ldg_sc4(p0, p0 + 8, p1, p1 + 8, a, b, c, d);
        float2 xv = {0.f, 0.f};
        if (xs >= 0) xv = *(const float2*)(x + ((long)(gb * 16 + sr) * TIN + xs) * FF + sc16 * 2);
        *(uint4*)(Atile + sr * ASTRIDE + sc16 * 16) = a;
        *(uint4*)(Atile + sr * ASTRIDE + sc16 * 16 + 8) = b;
        *(uint4*)(Atile + sr * ASTRIDE + 256 + sc16 * 16) = c;
        *(uint4*)(Atile + sr * ASTRIDE + 256 + sc16 * 16 + 8) = d;
        if (xs >= 0) {
            unsigned pv = (unsigned)f2bf(xv.x) | ((unsigned)f2bf(xv.y) << 16);
            *(unsigned*)(Xtile + sr * XSTRIDE + sc16 * 2) = pv;
        }
    };
    auto stageOne = [&](const unsigned short* src, int colbase) {
        const unsigned short* p = src + (long)(gb * 16 + sr) * 256 + sc16 * 16;
        uint4 a, b;
        ldg_sc2(p, p + 8, a, b);
        *(uint4*)(Atile + sr * ASTRIDE + colbase + sc16 * 16) = a;
        *(uint4*)(Atile + sr * ASTRIDE + colbase + sc16 * 16 + 8) = b;
    };
    auto stageTwo = [&](const unsigned short* s0, int cb0, const unsigned short* s1, int cb1) {
        const unsigned short* p0 = s0 + (long)(gb * 16 + sr) * 256 + sc16 * 16;
        const unsigned short* p1 = s1 + (long)(gb * 16 + sr) * 256 + sc16 * 16;
        uint4 a, b, c, d;
        ldg_sc4(p0, p0 + 8, p1, p1 + 8, a, b, c, d);
        *(uint4*)(Atile + sr * ASTRIDE + cb0 + sc16 * 16) = a;
        *(uint4*)(Atile + sr * ASTRIDE + cb0 + sc16 * 16 + 8) = b;
        *(uint4*)(Atile + sr * ASTRIDE + cb1 + sc16 * 16) = c;
        *(uint4*)(Atile + sr * ASTRIDE + cb1 + sc16 * 16 + 8) = d;
    };
    auto stageZero = [&](int colbase) {
        uint4 z = {0u, 0u, 0u, 0u};
        *(uint4*)(Atile + sr * ASTRIDE + colbase + sc16 * 16) = z;
        *(uint4*)(Atile + sr * ASTRIDE + colbase + sc16 * 16 + 8) = z;
    };
    auto stageX = [&](int xs) {
        float2 xv = *(const float2*)(x + ((long)(gb * 16 + sr) * TIN + xs) * FF + sc16 * 2);
        unsigned pv = (unsigned)f2bf(xv.x) | ((unsigned)f2bf(xv.y) << 16);
        *(unsigned*)(Xtile + sr * XSTRIDE + sc16 * 2) = pv;
    };

    // MFMA phase, full K per wave; in-wave gate exchange; register cell;
    // wave-packed 8-byte coalesced h store (fix for R10's 2B scatter write-amp)
    auto phase = [&](const bf16x8* B, int KB, bool withX, const float* bias, int layer,
                     unsigned short* hdst, bool addY0) {
        f32x4 acc = {0.f, 0.f, 0.f, 0.f};
        f32x4 acc2 = {0.f, 0.f, 0.f, 0.f};
        #pragma unroll
        for (int kb = 0; kb < 16; ++kb) {
            if (kb < KB) {
                bf16x8 a;
                if (withX && kb == 0) a = *(const bf16x8*)(Xtile + arow * XSTRIDE + ak);
                else {
                    const int koff = (withX ? (kb - 1) : kb) * 32;
                    a = *(const bf16x8*)(Atile + arow * ASTRIDE + koff + ak);
                }
                if (kb & 1) acc2 = __builtin_amdgcn_mfma_f32_16x16x32_bf16(a, B[kb], acc2, 0, 0, 0);
                else        acc  = __builtin_amdgcn_mfma_f32_16x16x32_bf16(a, B[kb], acc,  0, 0, 0);
            }
        }
        if (addY0) {
            bf16x8 a = *(const bf16x8*)(Xtile + arow * XSTRIDE + ak);
            acc2 = __builtin_amdgcn_mfma_f32_16x16x32_bf16(a, Bx0, acc2, 0, 0, 0);
        }
        acc[0] += acc2[0]; acc[1] += acc2[1]; acc[2] += acc2[2]; acc[3] += acc2[3];
        // gate exchange: lane handles row offset g; partner role g^d sends acc[(g^d)^d]=acc[g]
        float own = sel4(acc, g);
        float t1 = __shfl_xor(sel4(acc, g ^ 1), 1);
        float t2 = __shfl_xor(sel4(acc, g ^ 2), 2);
        float t3 = __shfl_xor(sel4(acc, g ^ 3), 3);
        float xi = pick4(own, t1, t2, t3, g)     + bias[0];
        float xf = pick4(own, t1, t2, t3, g ^ 1) + bias[1];
        float xg = pick4(own, t1, t2, t3, g ^ 2) + bias[2];
        float xo = pick4(own, t1, t2, t3, g ^ 3) + bias[3];
        float c  = creg[layer];
        float cn = sigf(xf) * c + sigf(xi) * tanhfast(xg);
        creg[layer] = cn;
        float hv = sigf(xo) * tanhfast(cn);
        // pack 4 cols (this wave's hh quad) into one 8B store per row
        unsigned lo = f2bf(hv);
        unsigned hi = f2bf(__shfl_xor(hv, 4));          // col+1 (hq^1)
        unsigned d0 = lo | (hi << 16);                  // cols {0,1} of quad (valid for hq even)
        unsigned d1 = (unsigned)__shfl_xor((int)d0, 8); // cols {2,3} from hq^2
        if ((ln & 12) == 0) {                           // hq==0: 16 lanes, one per row
            unsigned long long v8 = (unsigned long long)d0 | ((unsigned long long)d1 << 32);
            __hip_atomic_store((unsigned long long*)(hdst + (long)myrow * 256 + gi * 16 + nt * 4),
                               v8, __ATOMIC_RELAXED, __HIP_MEMORY_SCOPE_AGENT);
        }
    };

    // ---- init: enc B-frags; h0(-1)=0 in Atile; Xtile = x(0) ----
    loadB(U_E0 + (long)gi * 18432, KB0, Brg0);
    loadB(U_E1 + (long)gi * 32768, KB1, Brg1);
    stageZero(0);
    stageX(0);
    __syncthreads();

    // ---- encoder: 1 gsync/step ----
    for (int s = 0; s < TIN; ++s) {
        const int rp = s & 1, wp = rp ^ 1;
        phase(Brg0, KB0, true, bE0, 0, wsu + U_H0 + (long)wp * HPAR, false);
        gsync();                                   // publishes h0(s) (+ h1(s-1) earlier)
        stageEnc(h0u + (long)wp * HPAR, h1u + (long)rp * HPAR, (s + 1 < TIN) ? s + 1 : -1);
        __syncthreads();
        phase(Brg1, KB1, false, bE1, 1, wsu + U_H1 + (long)wp * HPAR, false);
    }

    // ---- pre-decoder: dec B-frags, Bx0, y0 -> Xtile ----
    loadB(U_D0 + (long)gi * 32768, KB1, Brg0);
    loadB(U_D1 + (long)gi * 32768, KB1, Brg1);
    Bx0 = *(const bf16x8*)(wsu + U_DX + (long)gi * 2048 + ((long)nt * 64 + ln) * 8);
    stageX(TIN - 1);                               // y0 = x[:, -1, :]

    // ---- decoder: 2 gsyncs/step; h0(s-1) persists in Atile cols 0..255 ----
    for (int s = TIN; s < TIN + TOUT; ++s) {
        const int wp = (s & 1) ^ 1, td = s - TIN;
        gsync();                                   // publishes h1(s-1)
        if (td == 0) stageZero(256);               // W_eff·0; y0 via addY0
        else stageOne(hdu + (long)(td - 1) * HPAR, 256);
        __syncthreads();
        phase(Brg0, KB1, false, (td == 0) ? bD0p : bDe, 0,
              wsu + U_H0 + (long)wp * HPAR, td == 0);
        gsync();                                   // publishes h0(s)
        if (td == 0) stageTwo(h0u + (long)wp * HPAR, 0, h1u + 0 * HPAR, 256);
        else stageOne(h0u + (long)wp * HPAR, 0);
        __syncthreads();
        phase(Brg1, KB1, false, bD1, 1, wsu + U_HD + (long)td * HPAR, false);
    }

    // ---- final sync: all h1dec published ----
    gsync();

    // ---- deferred y pass: f = {2gi, 2gi+1}, rows of gb; shuffle-reduce K over 16 lanes ----
    {
        const int r = t >> 4, kc = t & 15;
        const int f0 = gi * 2, f1 = f0 + 1;
        float w0[16], w1[16];
        #pragma unroll
        for (int i = 0; i < 16; ++i) {
            w0[i] = Wout[(long)f0 * 256 + kc * 16 + i];
            w1[i] = Wout[(long)f1 * 256 + kc * 16 + i];
        }
        const float bo0 = bout[f0], bo1 = bout[f1];
        for (int td = 0; td < TOUT; ++td) {
            const unsigned short* hp = hdu + (long)td * HPAR + (long)(gb * 16 + r) * 256 + kc * 16;
            uint4 ua = *(const uint4*)hp;
            uint4 ub = *(const uint4*)(hp + 8);
            unsigned wds[8] = {ua.x, ua.y, ua.z, ua.w, ub.x, ub.y, ub.z, ub.w};
            float a0 = 0.f, a1 = 0.f;
            #pragma unroll
            for (int j = 0; j < 8; ++j) {
                float lo = __uint_as_float(wds[j] << 16);
                float hi = __uint_as_float(wds[j] & 0xffff0000u);
                a0 = fmaf(lo, w0[2 * j], a0); a0 = fmaf(hi, w0[2 * j + 1], a0);
                a1 = fmaf(lo, w1[2 * j], a1); a1 = fmaf(hi, w1[2 * j + 1], a1);
            }
            #pragma unroll
            for (int off = 1; off < 16; off <<= 1) {
                a0 += __shfl_xor(a0, off);
                a1 += __shfl_xor(a1, off);
            }
            if (kc == 0) {
                float2 yv = {a0 + bo0, a1 + bo1};
                *(float2*)(out + ((long)(gb * 16 + r) * TOUT + td) * FF + f0) = yv;
            }
        }
    }
}

extern "C" void kernel_launch(void* const* d_in, const int* in_sizes, int n_in,
                              void* d_out, int out_size, void* d_ws, size_t ws_size,
                              hipStream_t stream) {
    const float* x     = (const float*)d_in[0];
    const float* eWih0 = (const float*)d_in[1];
    const float* eWhh0 = (const float*)d_in[2];
    const float* eb0   = (const float*)d_in[3];
    const float* eWih1 = (const float*)d_in[4];
    const float* eWhh1 = (const float*)d_in[5];
    const float* eb1   = (const float*)d_in[6];
    const float* dWih0 = (const float*)d_in[7];
    const float* dWhh0 = (const float*)d_in[8];
    const float* db0   = (const float*)d_in[9];
    const float* dWih1 = (const float*)d_in[10];
    const float* dWhh1 = (const float*)d_in[11];
    const float* db1   = (const float*)d_in[12];
    const float* dWout = (const float*)d_in[13];
    const float* dbout = (const float*)d_in[14];
    float* ws = (float*)d_ws;
    float* out = (float*)d_out;

    prep_kernel<<<1024, 256, 0, stream>>>(eWih0, eWhh0, eWih1, eWhh1,
                                          dWih0, dWhh0, dWih1, dWhh1, dWout, ws);
    lstm_main<<<NGS * NBG, TPB, 0, stream>>>(x, eb0, eb1, db0, db1,
                                             dWout, dbout, dWih0, ws, out);
}

// Round 12
// 1960.850 us; speedup vs baseline: 2.5734x; 2.4829x over previous
//
#include <hip/hip_runtime.h>
#include <hip/hip_bf16.h>

// Problem dims
#define BB   256
#define TIN  336
#define TOUT 96
#define FF   32
#define HH   256

#define NGS 16   // gate-column slices (gi)
#define NBG 16   // batch groups (gb)
#define RPG 16   // batch rows per group
#define TPB 256  // 4 waves; wave nt owns 16 cols (4 hh x 4 gates), full K

#define KB0 9        // enc L0: K=288 = [x(32) | h0(256)]
#define KB1 16       // K=512 phases
#define ASTRIDE 520  // A-tile row stride (bf16)
#define XSTRIDE 40   // X-tile row stride (bf16)

// ws layout in ushort units. Weight regions: [gi][nt][kb][lane][8], col cl=(hh_l<<2)|gate
#define N_E0   294912                 // 16*4*9*64*8
#define N_K512 524288                 // 16*4*16*64*8
#define N_DX   32768                  // 16*4*1*64*8
#define U_E0   0
#define U_E1   (U_E0 + N_E0)          // 294912  enc L1
#define U_D0   (U_E1 + N_K512)        // 819200  dec L0' = [Whh0 | W_eff]
#define U_D1   (U_D0 + N_K512)        // 1343488 dec L1
#define U_DX   (U_D1 + N_K512)        // 1867776 dec Wih0 (K=32)
#define U_END  (U_DX + N_DX)          // 1900544
#define HPAR   65536                  // one parity buffer: 256x256 bf16
#define U_H0   U_END                  // h0 parity x2
#define U_H1   (U_H0 + 2*HPAR)       // h1 parity x2 (encoder)
#define U_HD   (U_H1 + 2*HPAR)       // decoder h1 per-step x96
#define U_CTR  (U_HD + 96*HPAR)      // flags: [gb][32 dwords], 16 used
#define U_ZEND (U_CTR + 4096)

typedef __bf16 bf16x8 __attribute__((ext_vector_type(8)));
typedef float  f32x4  __attribute__((ext_vector_type(4)));

__device__ __forceinline__ float sigf(float x) { return 1.f / (1.f + __expf(-x)); }
__device__ __forceinline__ float tanhfast(float x) { return 1.f - 2.f / (__expf(2.f * x) + 1.f); }
__device__ __forceinline__ unsigned short f2bf(float f) {   // RNE bf16
    union { float f; unsigned u; } v; v.f = f;
    unsigned r = v.u + 0x7FFF + ((v.u >> 16) & 1);
    return (unsigned short)(r >> 16);
}
__device__ __forceinline__ float sel4(f32x4 a, int i) {
    return i == 0 ? a[0] : (i == 1 ? a[1] : (i == 2 ? a[2] : a[3]));
}
__device__ __forceinline__ float pick4(float a0, float a1, float a2, float a3, int i) {
    return i == 0 ? a0 : (i == 1 ? a1 : (i == 2 ? a2 : a3));
}
// coherence-point loads (bypass L1/L2); pair with write-through producer stores
__device__ __forceinline__ void ldg_sc2(const void* p0, const void* p1, uint4& a, uint4& b) {
    asm volatile("global_load_dwordx4 %0, %2, off sc0 sc1\n\t"
                 "global_load_dwordx4 %1, %3, off sc0 sc1\n\t"
                 "s_waitcnt vmcnt(0)"
                 : "=v"(a), "=v"(b) : "v"(p0), "v"(p1) : "memory");
}
__device__ __forceinline__ void ldg_sc4(const void* p0, const void* p1,
                                        const void* p2, const void* p3,
                                        uint4& a, uint4& b, uint4& c, uint4& d) {
    asm volatile("global_load_dwordx4 %0, %4, off sc0 sc1\n\t"
                 "global_load_dwordx4 %1, %5, off sc0 sc1\n\t"
                 "global_load_dwordx4 %2, %6, off sc0 sc1\n\t"
                 "global_load_dwordx4 %3, %7, off sc0 sc1\n\t"
                 "s_waitcnt vmcnt(0)"
                 : "=v"(a), "=v"(b), "=v"(c), "=v"(d)
                 : "v"(p0), "v"(p1), "v"(p2), "v"(p3) : "memory");
}

// ---- prep: bf16 MFMA-fragment weights, col map cl=(hh_l<<2)|gate; zero h/flags ----
__global__ void prep_kernel(const float* __restrict__ eWih0, const float* __restrict__ eWhh0,
                            const float* __restrict__ eWih1, const float* __restrict__ eWhh1,
                            const float* __restrict__ dWih0, const float* __restrict__ dWhh0,
                            const float* __restrict__ dWih1, const float* __restrict__ dWhh1,
                            const float* __restrict__ Wout,  float* __restrict__ wsf)
{
    unsigned short* wsu = (unsigned short*)wsf;
    for (long u = (long)blockIdx.x * blockDim.x + threadIdx.x; u < (long)U_END;
         u += (long)gridDim.x * blockDim.x) {
        int region; long l;
        if (u < U_E1)      { region = 0; l = u - U_E0; }
        else if (u < U_D0) { region = 1; l = u - U_E1; }
        else if (u < U_D1) { region = 2; l = u - U_D0; }
        else if (u < U_DX) { region = 3; l = u - U_D1; }
        else               { region = 4; l = u - U_DX; }
        const int KB = (region == 0) ? KB0 : (region == 4 ? 1 : KB1);
        int j = (int)(l & 7), lane = (int)((l >> 3) & 63);
        long rem = l >> 9;
        int kb = (int)(rem % KB), q = (int)(rem / KB);
        int nt = q & 3, gi = q >> 2;
        int k  = kb * 32 + ((lane >> 4) << 3) + j;
        int cl = lane & 15;
        int gate = cl & 3, hh = nt * 4 + (cl >> 2);
        int gj = gate * 256 + gi * 16 + hh;
        float v;
        if (region == 0)      v = (k < 32)  ? eWih0[gj * 32 + k]  : eWhh0[gj * 256 + (k - 32)];
        else if (region == 1) v = (k < 256) ? eWih1[gj * 256 + k] : eWhh1[gj * 256 + (k - 256)];
        else if (region == 2) {
            if (k < 256) v = dWhh0[gj * 256 + k];
            else {                               // W_eff = dWih0 . Wout
                float acc = 0.f; int kk = k - 256;
                #pragma unroll 8
                for (int f = 0; f < 32; ++f) acc += dWih0[gj * 32 + f] * Wout[f * 256 + kk];
                v = acc;
            }
        }
        else if (region == 3) v = (k < 256) ? dWih1[gj * 256 + k] : dWhh1[gj * 256 + (k - 256)];
        else                  v = dWih0[gj * 32 + k];      // K=32
        wsu[u] = f2bf(v);
    }
    for (long z = (long)blockIdx.x * blockDim.x + threadIdx.x; z < (long)(4 * HPAR);
         z += (long)gridDim.x * blockDim.x)
        wsu[U_H0 + z] = 0;
    for (long z = (long)blockIdx.x * blockDim.x + threadIdx.x; z < 4096;
         z += (long)gridDim.x * blockDim.x)
        wsu[U_CTR + z] = 0;
}

// ---- persistent seq2seq: 256 wgs x 4 waves; in-wave cell update; wg-flag gsync ----
__global__ __launch_bounds__(TPB, 1) void lstm_main(
    const float* __restrict__ x,
    const float* __restrict__ eb0, const float* __restrict__ eb1,
    const float* __restrict__ db0, const float* __restrict__ db1,
    const float* __restrict__ Wout, const float* __restrict__ bout,
    const float* __restrict__ dWih0,
    float* __restrict__ ws, float* __restrict__ out)
{
    const int gi = blockIdx.x >> 4;
    const int gb = blockIdx.x & 15;   // stride-16 blocks -> same XCD per group

    unsigned short* wsu = (unsigned short*)ws;
    const unsigned short* h0u = wsu + U_H0;
    const unsigned short* h1u = wsu + U_H1;
    const unsigned short* hdu = wsu + U_HD;
    unsigned* flagbase = (unsigned*)(wsu + U_CTR) + gb * 32;   // 16 wg-flags, one 64B line

    const int t  = threadIdx.x;
    const int wv = t >> 6;            // wave = N-tile nt
    const int ln = t & 63;
    const int nt = wv;
    const int arow = ln & 15, ak = (ln >> 4) << 3;
    const int g = ln & 3;             // gate role
    const int hh = nt * 4 + ((ln >> 2) & 3);
    const int myrow = gb * 16 + (ln >> 4) * 4 + g;     // row this lane updates

    __shared__ __align__(16) unsigned short Atile[16 * ASTRIDE];   // 16.25 KB
    __shared__ __align__(16) unsigned short Xtile[16 * XSTRIDE];   // 1.25 KB

    // per-lane biases (gates 0..3 at (gi,hh))
    float bE0[4], bE1[4], bD0p[4], bDe[4], bD1[4];
    #pragma unroll
    for (int gg = 0; gg < 4; ++gg) {
        const int gj = gg * 256 + gi * 16 + hh;
        bE0[gg] = eb0[gj]; bE1[gg] = eb1[gj]; bD0p[gg] = db0[gj]; bD1[gg] = db1[gj];
        float be = db0[gj];
        #pragma unroll 8
        for (int f = 0; f < 32; ++f) be += dWih0[gj * 32 + f] * bout[f];
        bDe[gg] = be;
    }
    float creg[2] = {0.f, 0.f};       // register cell state (this lane's row,hh)

    // B fragments MUST be register-resident: compile-time indices only (fix for R11 scratch)
    bf16x8 Brg0[16], Brg1[16], Bx0;
    auto loadB = [&](long ubase, int KB, bf16x8* B) {
        #pragma unroll
        for (int i = 0; i < 16; ++i)
            if (i < KB)
                B[i] = *(const bf16x8*)(wsu + ubase + ((long)(nt * KB + i) * 64 + ln) * 8);
    };

    int posts = 0;
    // wg-level flag + wave0-only poll of 16 flags (one line) — kills R11's poll storm
    auto gsync = [&]() {
        ++posts;
        asm volatile("s_waitcnt vmcnt(0)" ::: "memory");   // own h-stores acked at IC
        __syncthreads();                                   // all 4 waves drained
        if (t == 0)
            __hip_atomic_store(flagbase + gi, (unsigned)posts,
                               __ATOMIC_RELAXED, __HIP_MEMORY_SCOPE_AGENT);
        if (wv == 0) {
            for (;;) {
                unsigned v = __hip_atomic_load(flagbase + (ln & 15), __ATOMIC_RELAXED,
                                               __HIP_MEMORY_SCOPE_AGENT);
                if (__all((int)(v >= (unsigned)posts))) break;
                __builtin_amdgcn_s_sleep(1);
            }
        }
        __syncthreads();
    };

    // stage helpers: 256 threads, r = t>>4, c16 = t&15 (32B chunk per row)
    const int sr = t >> 4, sc16 = t & 15;
    auto stageEnc = [&](const unsigned short* h0src, const unsigned short* h1src, int xs) {
        const unsigned short* p0 = h0src + (long)(gb * 16 + sr) * 256 + sc16 * 16;
        const unsigned short* p1 = h1src + (long)(gb * 16 + sr) * 256 + sc16 * 16;
        uint4 a, b, c, d;
        ldg_sc4(p0, p0 + 8, p1, p1 + 8, a, b, c, d);
        float2 xv = {0.f, 0.f};
        if (xs >= 0) xv = *(const float2*)(x + ((long)(gb * 16 + sr) * TIN + xs) * FF + sc16 * 2);
        *(uint4*)(Atile + sr * ASTRIDE + sc16 * 16) = a;
        *(uint4*)(Atile + sr * ASTRIDE + sc16 * 16 + 8) = b;
        *(uint4*)(Atile + sr * ASTRIDE + 256 + sc16 * 16) = c;
        *(uint4*)(Atile + sr * ASTRIDE + 256 + sc16 * 16 + 8) = d;
        if (xs >= 0) {
            unsigned pv = (unsigned)f2bf(xv.x) | ((unsigned)f2bf(xv.y) << 16);
            *(unsigned*)(Xtile + sr * XSTRIDE + sc16 * 2) = pv;
        }
    };
    auto stageOne = [&](const unsigned short* src, int colbase) {
        const unsigned short* p = src + (long)(gb * 16 + sr) * 256 + sc16 * 16;
        uint4 a, b;
        ldg_sc2(p, p + 8, a, b);
        *(uint4*)(Atile + sr * ASTRIDE + colbase + sc16 * 16) = a;
        *(uint4*)(Atile + sr * ASTRIDE + colbase + sc16 * 16 + 8) = b;
    };
    auto stageTwo = [&](const unsigned short* s0, int cb0, const unsigned short* s1, int cb1) {
        const unsigned short* p0 = s0 + (long)(gb * 16 + sr) * 256 + sc16 * 16;
        const unsigned short* p1 = s1 + (long)(gb * 16 + sr) * 256 + sc16 * 16;
        uint4 a, b, c, d;
        ldg_sc4(p0, p0 + 8, p1, p1 + 8, a, b, c, d);
        *(uint4*)(Atile + sr * ASTRIDE + cb0 + sc16 * 16) = a;
        *(uint4*)(Atile + sr * ASTRIDE + cb0 + sc16 * 16 + 8) = b;
        *(uint4*)(Atile + sr * ASTRIDE + cb1 + sc16 * 16) = c;
        *(uint4*)(Atile + sr * ASTRIDE + cb1 + sc16 * 16 + 8) = d;
    };
    auto stageZero = [&](int colbase) {
        uint4 z = {0u, 0u, 0u, 0u};
        *(uint4*)(Atile + sr * ASTRIDE + colbase + sc16 * 16) = z;
        *(uint4*)(Atile + sr * ASTRIDE + colbase + sc16 * 16 + 8) = z;
    };
    auto stageX = [&](int xs) {
        float2 xv = *(const float2*)(x + ((long)(gb * 16 + sr) * TIN + xs) * FF + sc16 * 2);
        unsigned pv = (unsigned)f2bf(xv.x) | ((unsigned)f2bf(xv.y) << 16);
        *(unsigned*)(Xtile + sr * XSTRIDE + sc16 * 2) = pv;
    };

    // MFMA phase, full K per wave; in-wave gate exchange; register cell; packed 8B h store
    auto phase = [&](const bf16x8* B, int KB, bool withX, const float* bias, int layer,
                     unsigned short* hdst, bool addY0) {
        f32x4 acc = {0.f, 0.f, 0.f, 0.f};
        f32x4 acc2 = {0.f, 0.f, 0.f, 0.f};
        #pragma unroll
        for (int kb = 0; kb < 16; ++kb) {
            if (kb < KB) {
                bf16x8 a;
                if (withX && kb == 0) a = *(const bf16x8*)(Xtile + arow * XSTRIDE + ak);
                else {
                    const int koff = (withX ? (kb - 1) : kb) * 32;
                    a = *(const bf16x8*)(Atile + arow * ASTRIDE + koff + ak);
                }
                if (kb & 1) acc2 = __builtin_amdgcn_mfma_f32_16x16x32_bf16(a, B[kb], acc2, 0, 0, 0);
                else        acc  = __builtin_amdgcn_mfma_f32_16x16x32_bf16(a, B[kb], acc,  0, 0, 0);
            }
        }
        if (addY0) {
            bf16x8 a = *(const bf16x8*)(Xtile + arow * XSTRIDE + ak);
            acc2 = __builtin_amdgcn_mfma_f32_16x16x32_bf16(a, Bx0, acc2, 0, 0, 0);
        }
        acc[0] += acc2[0]; acc[1] += acc2[1]; acc[2] += acc2[2]; acc[3] += acc2[3];
        // gate exchange: lane handles row offset g; partner role g^d sends acc[(g^d)^d]=acc[g]
        float own = sel4(acc, g);
        float t1 = __shfl_xor(sel4(acc, g ^ 1), 1);
        float t2 = __shfl_xor(sel4(acc, g ^ 2), 2);
        float t3 = __shfl_xor(sel4(acc, g ^ 3), 3);
        float xi = pick4(own, t1, t2, t3, g)     + bias[0];
        float xf = pick4(own, t1, t2, t3, g ^ 1) + bias[1];
        float xg = pick4(own, t1, t2, t3, g ^ 2) + bias[2];
        float xo = pick4(own, t1, t2, t3, g ^ 3) + bias[3];
        float c  = creg[layer];
        float cn = sigf(xf) * c + sigf(xi) * tanhfast(xg);
        creg[layer] = cn;
        float hv = sigf(xo) * tanhfast(cn);
        // pack 4 cols (this wave's hh quad) into one 8B store per row
        unsigned lo = f2bf(hv);
        unsigned hi = f2bf(__shfl_xor(hv, 4));          // col+1 (hq^1)
        unsigned d0 = lo | (hi << 16);                  // cols {0,1} of quad (valid for hq even)
        unsigned d1 = (unsigned)__shfl_xor((int)d0, 8); // cols {2,3} from hq^2
        if ((ln & 12) == 0) {                           // hq==0: 16 lanes, one per row
            unsigned long long v8 = (unsigned long long)d0 | ((unsigned long long)d1 << 32);
            __hip_atomic_store((unsigned long long*)(hdst + (long)myrow * 256 + gi * 16 + nt * 4),
                               v8, __ATOMIC_RELAXED, __HIP_MEMORY_SCOPE_AGENT);
        }
    };

    // ---- init: enc B-frags; h0(-1)=0 in Atile; Xtile = x(0) ----
    loadB(U_E0 + (long)gi * 18432, KB0, Brg0);
    loadB(U_E1 + (long)gi * 32768, KB1, Brg1);
    stageZero(0);
    stageX(0);
    __syncthreads();

    // ---- encoder: 1 gsync/step ----
    for (int s = 0; s < TIN; ++s) {
        const int rp = s & 1, wp = rp ^ 1;
        phase(Brg0, KB0, true, bE0, 0, wsu + U_H0 + (long)wp * HPAR, false);
        gsync();                                   // publishes h0(s) (+ h1(s-1) earlier)
        stageEnc(h0u + (long)wp * HPAR, h1u + (long)rp * HPAR, (s + 1 < TIN) ? s + 1 : -1);
        __syncthreads();
        phase(Brg1, KB1, false, bE1, 1, wsu + U_H1 + (long)wp * HPAR, false);
    }

    // ---- pre-decoder: dec B-frags, Bx0, y0 -> Xtile ----
    loadB(U_D0 + (long)gi * 32768, KB1, Brg0);
    loadB(U_D1 + (long)gi * 32768, KB1, Brg1);
    Bx0 = *(const bf16x8*)(wsu + U_DX + (long)gi * 2048 + ((long)nt * 64 + ln) * 8);
    stageX(TIN - 1);                               // y0 = x[:, -1, :]

    // ---- decoder: 2 gsyncs/step; h0(s-1) persists in Atile cols 0..255 ----
    for (int s = TIN; s < TIN + TOUT; ++s) {
        const int wp = (s & 1) ^ 1, td = s - TIN;
        gsync();                                   // publishes h1(s-1)
        if (td == 0) stageZero(256);               // W_eff·0; y0 via addY0
        else stageOne(hdu + (long)(td - 1) * HPAR, 256);
        __syncthreads();
        phase(Brg0, KB1, false, (td == 0) ? bD0p : bDe, 0,
              wsu + U_H0 + (long)wp * HPAR, td == 0);
        gsync();                                   // publishes h0(s)
        if (td == 0) stageTwo(h0u + (long)wp * HPAR, 0, h1u + 0 * HPAR, 256);
        else stageOne(h0u + (long)wp * HPAR, 0);
        __syncthreads();
        phase(Brg1, KB1, false, bD1, 1, wsu + U_HD + (long)td * HPAR, false);
    }

    // ---- final sync: all h1dec published ----
    gsync();

    // ---- deferred y pass: f = {2gi, 2gi+1}, rows of gb; shuffle-reduce K over 16 lanes ----
    {
        const int r = t >> 4, kc = t & 15;
        const int f0 = gi * 2, f1 = f0 + 1;
        float w0[16], w1[16];
        #pragma unroll
        for (int i = 0; i < 16; ++i) {
            w0[i] = Wout[(long)f0 * 256 + kc * 16 + i];
            w1[i] = Wout[(long)f1 * 256 + kc * 16 + i];
        }
        const float bo0 = bout[f0], bo1 = bout[f1];
        for (int td = 0; td < TOUT; ++td) {
            const unsigned short* hp = hdu + (long)td * HPAR + (long)(gb * 16 + r) * 256 + kc * 16;
            uint4 ua = *(const uint4*)hp;
            uint4 ub = *(const uint4*)(hp + 8);
            unsigned wds[8] = {ua.x, ua.y, ua.z, ua.w, ub.x, ub.y, ub.z, ub.w};
            float a0 = 0.f, a1 = 0.f;
            #pragma unroll
            for (int j = 0; j < 8; ++j) {
                float lo = __uint_as_float(wds[j] << 16);
                float hi = __uint_as_float(wds[j] & 0xffff0000u);
                a0 = fmaf(lo, w0[2 * j], a0); a0 = fmaf(hi, w0[2 * j + 1], a0);
                a1 = fmaf(lo, w1[2 * j], a1); a1 = fmaf(hi, w1[2 * j + 1], a1);
            }
            #pragma unroll
            for (int off = 1; off < 16; off <<= 1) {
                a0 += __shfl_xor(a0, off);
                a1 += __shfl_xor(a1, off);
            }
            if (kc == 0) {
                float2 yv = {a0 + bo0, a1 + bo1};
                *(float2*)(out + ((long)(gb * 16 + r) * TOUT + td) * FF + f0) = yv;
            }
        }
    }
}

extern "C" void kernel_launch(void* const* d_in, const int* in_sizes, int n_in,
                              void* d_out, int out_size, void* d_ws, size_t ws_size,
                              hipStream_t stream) {
    const float* x     = (const float*)d_in[0];
    const float* eWih0 = (const float*)d_in[1];
    const float* eWhh0 = (const float*)d_in[2];
    const float* eb0   = (const float*)d_in[3];
    const float* eWih1 = (const float*)d_in[4];
    const float* eWhh1 = (const float*)d_in[5];
    const float* eb1   = (const float*)d_in[6];
    const float* dWih0 = (const float*)d_in[7];
    const float* dWhh0 = (const float*)d_in[8];
    const float* db0   = (const float*)d_in[9];
    const float* dWih1 = (const float*)d_in[10];
    const float* dWhh1 = (const float*)d_in[11];
    const float* db1   = (const float*)d_in[12];
    const float* dWout = (const float*)d_in[13];
    const float* dbout = (const float*)d_in[14];
    float* ws = (float*)d_ws;
    float* out = (float*)d_out;

    prep_kernel<<<1024, 256, 0, stream>>>(eWih0, eWhh0, eWih1, eWhh1,
                                          dWih0, dWhh0, dWih1, dWhh1, dWout, ws);
    lstm_main<<<NGS * NBG, TPB, 0, stream>>>(x, eb0, eb1, db0, db1,
                                             dWout, dbout, dWih0, ws, out);
}